// Round 1
// baseline (482.092 us; speedup 1.0000x reference)
//
#include <hip/hip_runtime.h>

// Depth-to-space (CRD / pixel-shuffle), k=3, fp32.
// in:  (B=32, C=9, H=512, W=512)   out: (B=32, 1, 1536, 1536)
// out[b, 0, i*3+r, j*3+s] = in[b, r*3+s, i, j]

namespace {
constexpr int B = 32;
constexpr int K = 3;
constexpr int H = 512;
constexpr int W = 512;
constexpr int HW = H * W;          // 262144 floats per plane
constexpr int OW = K * W;          // 1536
constexpr int JBLK = W / 4;        // 128 float4-chunks per input row
// one thread per (b, r, i, jblk): 32 * 3 * 512 * 128 = 6,291,456 threads
constexpr int TOTAL_THREADS = B * K * H * JBLK;
}

__global__ __launch_bounds__(256) void d2s_k3_kernel(
    const float* __restrict__ in, float* __restrict__ out) {
    int t = blockIdx.x * blockDim.x + threadIdx.x;

    int jblk = t & (JBLK - 1);     // fastest: keeps wave contiguous in j
    int rest = t >> 7;             // i + H*(r + 3*b)
    int i    = rest & (H - 1);
    int rb   = rest >> 9;          // r + 3*b, in [0, 96)
    int b    = rb / 3;             // compiler magic-mul
    int r    = rb - 3 * b;

    // Input: three planes c = 3r+0, 3r+1, 3r+2, same (i, 4*jblk).
    const float4* p =
        reinterpret_cast<const float4*>(in + ((b * 9 + r * 3) * HW + i * W)) + jblk;
    float4 a0 = p[0];
    float4 a1 = p[HW / 4];
    float4 a2 = p[2 * (HW / 4)];

    // Interleave (j-major, s-minor): out[3j+s] = plane_s[j]
    float4 o0 = make_float4(a0.x, a1.x, a2.x, a0.y);
    float4 o1 = make_float4(a1.y, a2.y, a0.z, a1.z);
    float4 o2 = make_float4(a2.z, a0.w, a1.w, a2.w);

    // Output row (i*3 + r), cols [jblk*12, jblk*12+12)
    float4* q = reinterpret_cast<float4*>(
        out + (b * (K * H * OW) + (i * 3 + r) * OW)) + jblk * 3;
    q[0] = o0;
    q[1] = o1;
    q[2] = o2;
}

extern "C" void kernel_launch(void* const* d_in, const int* in_sizes, int n_in,
                              void* d_out, int out_size, void* d_ws, size_t ws_size,
                              hipStream_t stream) {
    const float* in = (const float*)d_in[0];
    float* out = (float*)d_out;
    // d_in[1] is kernel_size (=3), shapes are fixed by the bench — hardcoded.
    constexpr int block = 256;
    constexpr int grid = TOTAL_THREADS / block;  // 24576
    d2s_k3_kernel<<<grid, block, 0, stream>>>(in, out);
}